// Round 12
// baseline (272.176 us; speedup 1.0000x reference)
//
#include <hip/hip_runtime.h>
#include <math.h>

#define NB1 8192
#define NB2 12288
#define DD  128

typedef unsigned long long u64;
typedef unsigned short ushort_t;
typedef __attribute__((ext_vector_type(8))) short short8;
typedef __attribute__((ext_vector_type(8))) _Float16 half8;
typedef __attribute__((ext_vector_type(4))) float f32x4;

__device__ __forceinline__ float bigf() { return __uint_as_float(0x7F7F0000u); }

__device__ __forceinline__ unsigned orderbits(float v) {
    unsigned b = __float_as_uint(v);
    return b ^ ((unsigned)((int)b >> 31) | 0x80000000u);
}
__device__ __forceinline__ float unorderbits(unsigned k) {
    unsigned b = (k & 0x80000000u) ? (k ^ 0x80000000u) : ~k;
    return __uint_as_float(b);
}
__device__ __forceinline__ u64 packkey(float v, unsigned idx) {
    return ((u64)orderbits(v) << 32) | idx;
}
__device__ __forceinline__ u64 umin64(u64 a, u64 b) { return a < b ? a : b; }

__device__ __forceinline__ ushort_t bf_rn(float x) {
    unsigned u = __float_as_uint(x);
    return (ushort_t)((u + 0x7FFFu + ((u >> 16) & 1u)) >> 16);
}
__device__ __forceinline__ float bf_up(ushort_t h) {
    return __uint_as_float(((unsigned)h) << 16);
}
__device__ __forceinline__ int fswz(int r) { return (r + (r >> 2)) & 3; }
__device__ __forceinline__ half8 ld8h(const _Float16* p) { return *(const half8*)p; }

// Kernel N: squared norms + init packed min arrays.
__global__ __launch_bounds__(256) void prep_kernel(
    const float* __restrict__ d1, const float* __restrict__ d2,
    float* __restrict__ sq1, float* __restrict__ sq2,
    u64* __restrict__ rowmin, u64* __restrict__ colmin) {
    int t = blockIdx.x * 256 + threadIdx.x;
    if (t < NB1) {
        rowmin[t] = ~0ull;
        const float4* p = (const float4*)(d1 + (size_t)t * DD);
        float s = 0.f;
        #pragma unroll
        for (int c = 0; c < DD / 4; ++c) {
            float4 v = p[c];
            s = fmaf(v.x, v.x, s); s = fmaf(v.y, v.y, s);
            s = fmaf(v.z, v.z, s); s = fmaf(v.w, v.w, s);
        }
        sq1[t] = s;
    }
    if (t < NB2) {
        colmin[t] = ~0ull;
        const float4* p = (const float4*)(d2 + (size_t)t * DD);
        float s = 0.f;
        #pragma unroll
        for (int c = 0; c < DD / 4; ++c) {
            float4 v = p[c];
            s = fmaf(v.x, v.x, s); s = fmaf(v.y, v.y, s);
            s = fmaf(v.z, v.z, s); s = fmaf(v.w, v.w, s);
        }
        sq2[t] = s;
    }
}

// Kernel S16: 2-way f16 split into FRAGMENT-MAJOR planes (plane-separated,
// round-8 geometry). x = h + m; store h and m' = f16(2048*m) (always normal
// f16 -> no subnormal/FTZ hazard; consumer multiplies back by 2^-11 exactly).
// Tile lt = rb*4+kc covers rows rb*16.., k kc*32.., 512 f16 in exact MFMA
// lane order: lane l holds row rb*16+(l&15), k kc*32+(l>>4)*8 + 0..7.
// A tasks 2048, B tasks 3072; one wave per tile.
__global__ __launch_bounds__(256) void split_frag16_kernel(
    const float* __restrict__ d1, const float* __restrict__ d2,
    _Float16* __restrict__ Af, _Float16* __restrict__ Bf) {
    int t = blockIdx.x * 256 + threadIdx.x;    // 0 .. 327679
    int lane = t & 63;
    int task = t >> 6;                          // 0 .. 5119
    bool isA = task < 2048;
    int lt = isA ? task : task - 2048;
    int rb = lt >> 2;
    int kc = lt & 3;
    int row = rb * 16 + (lane & 15);
    int kst = kc * 32 + (lane >> 4) * 8;
    const float* src = (isA ? d1 : d2) + (size_t)row * DD + kst;
    const size_t plane = (size_t)(isA ? NB1 : NB2) * DD;   // f16 per plane
    _Float16* dst = (isA ? Af : Bf) + ((size_t)lt * 512 + lane * 8);

    half8 H, M;
    #pragma unroll
    for (int e = 0; e < 8; ++e) {
        float x = src[e];
        _Float16 h = (_Float16)x;
        float m = x - (float)h;                 // exact (Sterbenz)
        H[e] = h;
        M[e] = (_Float16)(m * 2048.0f);
    }
    *(half8*)(dst)         = H;
    *(half8*)(dst + plane) = M;
}

// Kernel T6: barrier-free f16 MFMA distance tiles (round-8 structure).
// Block 256 = 4 waves (2x2 of 64x64 wave tiles), block tile 128x128.
// Per kc: 8 B-frag loads + 8 A-frag loads (A pipelined one mi ahead),
// 48 MFMAs (16 frags x 3 products hh / h*m' / m'*h). Dual accumulators:
// acc0 = hh, acc1 = scaled corrections; dot = acc0 + acc1 * 2^-11 (exact
// scale). XCD-chunked swizzle (8x8-block chunks, per-chunk working set
// ~1 MB << 4 MiB XCD-L2) carried from round 8.
__global__ __launch_bounds__(256) void mfma_tile6_kernel(
    const _Float16* __restrict__ Af, const _Float16* __restrict__ Bf,
    const float* __restrict__ sq1, const float* __restrict__ sq2,
    u64* __restrict__ rowmin, u64* __restrict__ colmin)
{
    const int bid  = blockIdx.x;
    const int xcd  = bid & 7;
    const int t_   = bid >> 3;          // 0..767 per xcd
    const int kch  = t_ >> 6;           // 0..11  j-chunk index
    const int wdn  = t_ & 63;
    const int j0b  = (kch * 8 + (wdn & 7)) * 128;
    const int i0b  = (xcd * 8 + (wdn >> 3)) * 128;

    const int tid  = threadIdx.x;
    const int lane = tid & 63;
    const int wid  = tid >> 6;
    const int wr   = wid >> 1;
    const int wc   = wid & 1;
    const int lrow = lane & 15;
    const int lg   = lane >> 4;

    // Tile (rb, kc) at rb*2048 + kc*512 f16; comp plane strides below.
    const _Float16* abase = Af + ((size_t)((i0b >> 4) + wr * 4) * 2048) + lane * 8;
    const _Float16* bbase = Bf + ((size_t)((j0b >> 4) + wc * 4) * 2048) + lane * 8;
    const size_t paf = (size_t)NB1 * DD;    // f16 per A plane
    const size_t pbf = (size_t)NB2 * DD;    // f16 per B plane

    f32x4 acc0[4][4], acc1[4][4];
    #pragma unroll
    for (int mi = 0; mi < 4; ++mi)
        #pragma unroll
        for (int ni = 0; ni < 4; ++ni) {
            acc0[mi][ni] = (f32x4){0.f, 0.f, 0.f, 0.f};
            acc1[mi][ni] = (f32x4){0.f, 0.f, 0.f, 0.f};
        }

    #pragma unroll 1
    for (int kc = 0; kc < 4; ++kc) {
        const int ko = kc * 512;
        // All 8 B-fragments for this k-chunk.
        half8 bh[4], bm[4];
        #pragma unroll
        for (int ni = 0; ni < 4; ++ni) {
            bh[ni] = ld8h(bbase + ni * 2048 + ko);
            bm[ni] = ld8h(bbase + pbf + ni * 2048 + ko);
        }
        // A-fragments, pipelined one mi ahead.
        half8 ah0, am0, ah1, am1;
        ah0 = ld8h(abase + ko);
        am0 = ld8h(abase + paf + ko);
        #pragma unroll
        for (int mi = 0; mi < 4; ++mi) {
            if (mi < 3) {
                ah1 = ld8h(abase + (mi + 1) * 2048 + ko);
                am1 = ld8h(abase + paf + (mi + 1) * 2048 + ko);
            }
            #pragma unroll
            for (int ni = 0; ni < 4; ++ni) {
                acc0[mi][ni] = __builtin_amdgcn_mfma_f32_16x16x32_f16(ah0, bh[ni], acc0[mi][ni], 0, 0, 0);
                f32x4 t = acc1[mi][ni];
                t = __builtin_amdgcn_mfma_f32_16x16x32_f16(ah0, bm[ni], t, 0, 0, 0);
                t = __builtin_amdgcn_mfma_f32_16x16x32_f16(am0, bh[ni], t, 0, 0, 0);
                acc1[mi][ni] = t;
            }
            ah0 = ah1; am0 = am1;
        }
    }

    // ---- epilogue: combine chains, packed-min reductions.
    // dot = acc0 + acc1 * 2^-11 (exact power-of-2 scale).
    // C/D: row = (lane>>4)*4 + r + mi*16, col = lane&15 + ni*16.
    const float SC = 0.00048828125f;    // 2^-11
    float q2v[4];
    #pragma unroll
    for (int ni = 0; ni < 4; ++ni)
        q2v[ni] = sq2[j0b + wc * 64 + ni * 16 + lrow];
    float4 q1v[4];
    #pragma unroll
    for (int mi = 0; mi < 4; ++mi)
        q1v[mi] = *(const float4*)(sq1 + i0b + wr * 64 + mi * 16 + 4 * lg);

    #pragma unroll
    for (int mi = 0; mi < 4; ++mi)
        #pragma unroll
        for (int r = 0; r < 4; ++r) {
            u64 best = ~0ull;
            #pragma unroll
            for (int ni = 0; ni < 4; ++ni) {
                float d = fmaf(acc1[mi][ni][r], SC, acc0[mi][ni][r]);
                float kr = fmaf(-2.f, d, q2v[ni]);
                best = umin64(best, packkey(kr, (unsigned)(j0b + wc * 64 + ni * 16 + lrow)));
            }
            #pragma unroll
            for (int mask = 8; mask; mask >>= 1)
                best = umin64(best, __shfl_xor(best, mask));
            if (lrow == 0)
                atomicMin(&rowmin[i0b + wr * 64 + mi * 16 + 4 * lg + r], best);
        }

    #pragma unroll
    for (int ni = 0; ni < 4; ++ni) {
        u64 best = ~0ull;
        #pragma unroll
        for (int mi = 0; mi < 4; ++mi) {
            const float* q1p = (const float*)&q1v[mi];
            #pragma unroll
            for (int r = 0; r < 4; ++r) {
                float d = fmaf(acc1[mi][ni][r], SC, acc0[mi][ni][r]);
                float kc_ = fmaf(-2.f, d, q1p[r]);
                best = umin64(best, packkey(kc_, (unsigned)(i0b + wr * 64 + mi * 16 + 4 * lg + r)));
            }
        }
        best = umin64(best, __shfl_xor(best, 16));
        best = umin64(best, __shfl_xor(best, 32));
        if (lane < 16)
            atomicMin(&colmin[j0b + wc * 64 + ni * 16 + lrow], best);
    }
}

// ============================ fallback path ============================
// In-kernel bf16 3-way split LDS version (round 5); needs no ws planes.
__global__ __launch_bounds__(256) void mfma_tile_kernel(
    const float* __restrict__ d1, const float* __restrict__ d2,
    const float* __restrict__ sq1, const float* __restrict__ sq2,
    u64* __restrict__ rowmin, u64* __restrict__ colmin)
{
    __shared__ __align__(16) short lds[6 * 4096];
    const int tid = threadIdx.x;
    const int i0b = blockIdx.y * 128;
    const int j0b = blockIdx.x * 128;
    const int srow  = tid >> 1;
    const int shalf = tid & 1;
    const int sfr   = fswz(srow);
    const int sg0   = ((2 * shalf) ^ sfr) * 8;
    const int sg1   = ((2 * shalf + 1) ^ sfr) * 8;
    const float* gA = d1 + (size_t)(i0b + srow) * DD + shalf * 16;
    const float* gB = d2 + (size_t)(j0b + srow) * DD + shalf * 16;
    short* wA = lds + srow * 32;
    short* wB = lds + 3 * 4096 + srow * 32;
    const int lane = tid & 63;
    const int wid  = tid >> 6;
    const int wr   = wid >> 1;
    const int wc   = wid & 1;
    const int lrow = lane & 15;
    const int lg   = lane >> 4;
    const int gx   = (lg ^ fswz(lrow)) * 8;
    const int aoff = (wr * 64 + lrow) * 32 + gx;
    const int boff = 3 * 4096 + (wc * 64 + lrow) * 32 + gx;

    f32x4 acc[4][4];
    #pragma unroll
    for (int mi = 0; mi < 4; ++mi)
        #pragma unroll
        for (int ni = 0; ni < 4; ++ni)
            acc[mi][ni] = (f32x4){0.f, 0.f, 0.f, 0.f};

    for (int kc = 0; kc < 4; ++kc) {
        {
            const float* sp = gA + kc * 32;
            short8 H0, M0, L0, H1, M1, L1;
            #pragma unroll
            for (int e = 0; e < 8; ++e) {
                float x = sp[e];
                ushort_t h = bf_rn(x); float r1 = x - bf_up(h);
                ushort_t m = bf_rn(r1); float r2 = r1 - bf_up(m);
                H0[e] = (short)h; M0[e] = (short)m; L0[e] = (short)bf_rn(r2);
            }
            #pragma unroll
            for (int e = 0; e < 8; ++e) {
                float x = sp[8 + e];
                ushort_t h = bf_rn(x); float r1 = x - bf_up(h);
                ushort_t m = bf_rn(r1); float r2 = r1 - bf_up(m);
                H1[e] = (short)h; M1[e] = (short)m; L1[e] = (short)bf_rn(r2);
            }
            *(short8*)(wA + sg0)        = H0;
            *(short8*)(wA + sg1)        = H1;
            *(short8*)(wA + 4096 + sg0) = M0;
            *(short8*)(wA + 4096 + sg1) = M1;
            *(short8*)(wA + 8192 + sg0) = L0;
            *(short8*)(wA + 8192 + sg1) = L1;
        }
        {
            const float* sp = gB + kc * 32;
            short8 H0, M0, L0, H1, M1, L1;
            #pragma unroll
            for (int e = 0; e < 8; ++e) {
                float x = sp[e];
                ushort_t h = bf_rn(x); float r1 = x - bf_up(h);
                ushort_t m = bf_rn(r1); float r2 = r1 - bf_up(m);
                H0[e] = (short)h; M0[e] = (short)m; L0[e] = (short)bf_rn(r2);
            }
            #pragma unroll
            for (int e = 0; e < 8; ++e) {
                float x = sp[8 + e];
                ushort_t h = bf_rn(x); float r1 = x - bf_up(h);
                ushort_t m = bf_rn(r1); float r2 = r1 - bf_up(m);
                H1[e] = (short)h; M1[e] = (short)m; L1[e] = (short)bf_rn(r2);
            }
            *(short8*)(wB + sg0)        = H0;
            *(short8*)(wB + sg1)        = H1;
            *(short8*)(wB + 4096 + sg0) = M0;
            *(short8*)(wB + 4096 + sg1) = M1;
            *(short8*)(wB + 8192 + sg0) = L0;
            *(short8*)(wB + 8192 + sg1) = L1;
        }
        __syncthreads();
        short8 af[3][4], bfr[3][4];
        #pragma unroll
        for (int c = 0; c < 3; ++c)
            #pragma unroll
            for (int t = 0; t < 4; ++t) {
                af[c][t]  = *(const short8*)(lds + c * 4096 + aoff + t * 512);
                bfr[c][t] = *(const short8*)(lds + c * 4096 + boff + t * 512);
            }
        #pragma unroll
        for (int mi = 0; mi < 4; ++mi)
            #pragma unroll
            for (int ni = 0; ni < 4; ++ni) {
                f32x4 a = acc[mi][ni];
                a = __builtin_amdgcn_mfma_f32_16x16x32_bf16(af[0][mi], bfr[0][ni], a, 0, 0, 0);
                a = __builtin_amdgcn_mfma_f32_16x16x32_bf16(af[0][mi], bfr[1][ni], a, 0, 0, 0);
                a = __builtin_amdgcn_mfma_f32_16x16x32_bf16(af[1][mi], bfr[0][ni], a, 0, 0, 0);
                a = __builtin_amdgcn_mfma_f32_16x16x32_bf16(af[0][mi], bfr[2][ni], a, 0, 0, 0);
                a = __builtin_amdgcn_mfma_f32_16x16x32_bf16(af[1][mi], bfr[1][ni], a, 0, 0, 0);
                a = __builtin_amdgcn_mfma_f32_16x16x32_bf16(af[2][mi], bfr[0][ni], a, 0, 0, 0);
                acc[mi][ni] = a;
            }
        __syncthreads();
    }

    float q2v[4];
    #pragma unroll
    for (int ni = 0; ni < 4; ++ni)
        q2v[ni] = sq2[j0b + wc * 64 + ni * 16 + lrow];
    float4 q1v[4];
    #pragma unroll
    for (int mi = 0; mi < 4; ++mi)
        q1v[mi] = *(const float4*)(sq1 + i0b + wr * 64 + mi * 16 + 4 * lg);

    #pragma unroll
    for (int mi = 0; mi < 4; ++mi)
        #pragma unroll
        for (int r = 0; r < 4; ++r) {
            u64 best = ~0ull;
            #pragma unroll
            for (int ni = 0; ni < 4; ++ni) {
                float kr = fmaf(-2.f, acc[mi][ni][r], q2v[ni]);
                best = umin64(best, packkey(kr, (unsigned)(j0b + wc * 64 + ni * 16 + lrow)));
            }
            #pragma unroll
            for (int mask = 8; mask; mask >>= 1)
                best = umin64(best, __shfl_xor(best, mask));
            if (lrow == 0)
                atomicMin(&rowmin[i0b + wr * 64 + mi * 16 + 4 * lg + r], best);
        }
    #pragma unroll
    for (int ni = 0; ni < 4; ++ni) {
        u64 best = ~0ull;
        #pragma unroll
        for (int mi = 0; mi < 4; ++mi) {
            const float* q1p = (const float*)&q1v[mi];
            #pragma unroll
            for (int r = 0; r < 4; ++r) {
                float kc_ = fmaf(-2.f, acc[mi][ni][r], q1p[r]);
                best = umin64(best, packkey(kc_, (unsigned)(i0b + wr * 64 + mi * 16 + 4 * lg + r)));
            }
        }
        best = umin64(best, __shfl_xor(best, 16));
        best = umin64(best, __shfl_xor(best, 32));
        if (lane < 16)
            atomicMin(&colmin[j0b + wc * 64 + ni * 16 + lrow], best);
    }
}

// Kernel 3: assemble outputs (bigf() instead of +inf: inf-inf = NaN fails diff).
__global__ __launch_bounds__(256) void final_kernel(
    const float* __restrict__ sq1,
    const u64* __restrict__ rowmin, const u64* __restrict__ colmin,
    float* __restrict__ out) {
    int i = blockIdx.x * 256 + threadIdx.x;
    if (i >= NB1) return;
    u64 rm = rowmin[i];
    unsigned ju = (unsigned)(rm & 0xFFFFFFFFu);
    float kr = unorderbits((unsigned)(rm >> 32));
    float dist = sqrtf(fmaxf(sq1[i] + kr, 0.f));
    dist = fminf(dist, bigf());
    bool valid = (ju < (unsigned)NB2);
    int j = valid ? (int)ju : 0;
    u64 cm = colmin[j];
    int i2 = (int)(cm & 0xFFFFFFFFu);
    bool mut = valid && (i2 == i);
    out[i] = mut ? dist : bigf();
    out[NB1 + 2 * i]     = mut ? (float)i : -1.f;
    out[NB1 + 2 * i + 1] = mut ? (float)j : -1.f;
    out[NB1 + 2 * NB1 + i] = mut ? 1.f : 0.f;
}

extern "C" void kernel_launch(void* const* d_in, const int* in_sizes, int n_in,
                              void* d_out, int out_size, void* d_ws, size_t ws_size,
                              hipStream_t stream) {
    const float* d1 = (const float*)d_in[0];
    const float* d2 = (const float*)d_in[1];
    float* out = (float*)d_out;

    char* ws = (char*)d_ws;
    float* sq1    = (float*)(ws);
    float* sq2    = (float*)(ws + 32768);
    u64*   rowmin = (u64*)(ws + 81920);
    u64*   colmin = (u64*)(ws + 147456);
    _Float16* Af = (_Float16*)(ws + 245760);            // 2 planes x 2 MB = 4,194,304 B
    _Float16* Bf = (_Float16*)(ws + 245760 + 4194304);  // 2 planes x 3 MB = 6,291,456 B
    const size_t need = 245760 + 4194304 + 6291456;     // ~10.7 MB

    hipLaunchKernelGGL(prep_kernel, dim3((NB2 + 255) / 256), dim3(256), 0, stream,
                       d1, d2, sq1, sq2, rowmin, colmin);
    if (ws_size >= need) {
        hipLaunchKernelGGL(split_frag16_kernel, dim3(1280), dim3(256), 0, stream,
                           d1, d2, Af, Bf);
        hipLaunchKernelGGL(mfma_tile6_kernel, dim3(6144), dim3(256), 0, stream,
                           Af, Bf, sq1, sq2, rowmin, colmin);
    } else {
        hipLaunchKernelGGL(mfma_tile_kernel, dim3(NB2 / 128, NB1 / 128), dim3(256), 0, stream,
                           d1, d2, sq1, sq2, rowmin, colmin);
    }
    hipLaunchKernelGGL(final_kernel, dim3((NB1 + 255) / 256), dim3(256), 0, stream,
                       sq1, rowmin, colmin, out);
}

// Round 13
// 215.518 us; speedup vs baseline: 1.2629x; 1.2629x over previous
//
#include <hip/hip_runtime.h>
#include <math.h>

#define NB1 8192
#define NB2 12288
#define DD  128

typedef unsigned long long u64;
typedef unsigned short ushort_t;
typedef __attribute__((ext_vector_type(8))) short short8;
typedef __attribute__((ext_vector_type(8))) _Float16 half8;
typedef __attribute__((ext_vector_type(4))) float f32x4;

__device__ __forceinline__ float bigf() { return __uint_as_float(0x7F7F0000u); }

__device__ __forceinline__ unsigned orderbits(float v) {
    unsigned b = __float_as_uint(v);
    return b ^ ((unsigned)((int)b >> 31) | 0x80000000u);
}
__device__ __forceinline__ float unorderbits(unsigned k) {
    unsigned b = (k & 0x80000000u) ? (k ^ 0x80000000u) : ~k;
    return __uint_as_float(b);
}
__device__ __forceinline__ u64 packkey(float v, unsigned idx) {
    return ((u64)orderbits(v) << 32) | idx;
}
__device__ __forceinline__ u64 umin64(u64 a, u64 b) { return a < b ? a : b; }

__device__ __forceinline__ ushort_t bf_rn(float x) {
    unsigned u = __float_as_uint(x);
    return (ushort_t)((u + 0x7FFFu + ((u >> 16) & 1u)) >> 16);
}
__device__ __forceinline__ float bf_up(ushort_t h) {
    return __uint_as_float(((unsigned)h) << 16);
}
__device__ __forceinline__ int fswz(int r) { return (r + (r >> 2)) & 3; }
__device__ __forceinline__ half8 ld8h(const _Float16* p) { return *(const half8*)p; }

// Kernel N: squared norms + init packed min arrays.
__global__ __launch_bounds__(256) void prep_kernel(
    const float* __restrict__ d1, const float* __restrict__ d2,
    float* __restrict__ sq1, float* __restrict__ sq2,
    u64* __restrict__ rowmin, u64* __restrict__ colmin) {
    int t = blockIdx.x * 256 + threadIdx.x;
    if (t < NB1) {
        rowmin[t] = ~0ull;
        const float4* p = (const float4*)(d1 + (size_t)t * DD);
        float s = 0.f;
        #pragma unroll
        for (int c = 0; c < DD / 4; ++c) {
            float4 v = p[c];
            s = fmaf(v.x, v.x, s); s = fmaf(v.y, v.y, s);
            s = fmaf(v.z, v.z, s); s = fmaf(v.w, v.w, s);
        }
        sq1[t] = s;
    }
    if (t < NB2) {
        colmin[t] = ~0ull;
        const float4* p = (const float4*)(d2 + (size_t)t * DD);
        float s = 0.f;
        #pragma unroll
        for (int c = 0; c < DD / 4; ++c) {
            float4 v = p[c];
            s = fmaf(v.x, v.x, s); s = fmaf(v.y, v.y, s);
            s = fmaf(v.z, v.z, s); s = fmaf(v.w, v.w, s);
        }
        sq2[t] = s;
    }
}

// Kernel SE: 2-way f16 split into K-CONCATENATED fragment-major planes.
// Extended rows (K_eff = 384 = 12 k-chunks of 32):
//   A' = [ H | M~ | H~ ]   B' = [ H' | H~' | M~' ]
// with H = f16(x), m = x - H (exact), M~ = f16(2^8 m), H~ = f16(2^-8 H).
// GEMM over K=384 then yields  Sum hh' + Sum mh' + Sum hm'  in ONE chain
// (the 2^±8 factors cancel in the cross products; scales are exact).
// Subnormal H~ only for |h| < 2^-6 where the correction is <= 2^-18 * |h'|
// per element -> negligible even under FTZ. M~ <= 0.5 (no overflow).
// Tile lt = rb*12 + kc at base + lt*512 f16, exact MFMA lane order:
// lane l holds row rb*16+(l&15), k (kc&3)*32+(l>>4)*8 + 0..7 of region kc>>2.
// Tasks: A 512 rb x 12 kc = 6144; B 768 x 12 = 9216; one wave per tile.
__global__ __launch_bounds__(256) void split_ext16_kernel(
    const float* __restrict__ d1, const float* __restrict__ d2,
    _Float16* __restrict__ Af, _Float16* __restrict__ Bf) {
    int t = blockIdx.x * 256 + threadIdx.x;    // 0 .. 983039
    int lane = t & 63;
    int task = t >> 6;                          // 0 .. 15359
    bool isA = task < 6144;
    int lt = isA ? task : task - 6144;
    int rb = lt / 12;
    int kc = lt - rb * 12;
    int region = kc >> 2;                       // 0:H, then side-specific
    int row = rb * 16 + (lane & 15);
    int kst = (kc & 3) * 32 + (lane >> 4) * 8;
    const float* src = (isA ? d1 : d2) + (size_t)row * DD + kst;
    _Float16* dst = (isA ? Af : Bf) + ((size_t)lt * 512 + lane * 8);

    // A regions: 0->H, 1->M~, 2->H~.  B regions: 0->H, 1->H~, 2->M~.
    bool wantM = isA ? (region == 1) : (region == 2);
    half8 V;
    #pragma unroll
    for (int e = 0; e < 8; ++e) {
        float x = src[e];
        _Float16 hf = (_Float16)x;
        float h = (float)hf;
        float v;
        if (region == 0)      v = x;                       // f16(x) on store
        else if (wantM)       v = (x - h) * 256.0f;        // M~ = 2^8 m
        else                  v = h * 0.00390625f;         // H~ = 2^-8 h
        V[e] = (_Float16)v;
    }
    *(half8*)dst = V;
}

// Kernel T7: barrier-free f16 MFMA distance tiles (round-8 structure,
// single accumulator chain). Block 256 = 4 waves (2x2 of 64x64 wave
// tiles), block tile 128x128. 12 k-chunks of 32; per kc: 4 B-frag loads
// + 4 A-frag loads (A pipelined one mi ahead) + 16 MFMAs.
// XCD-chunked block swizzle (8x8-block chunks, working set ~3 MB < 4 MiB
// XCD-L2) carried from round 8.
__global__ __launch_bounds__(256) void mfma_tile7_kernel(
    const _Float16* __restrict__ Af, const _Float16* __restrict__ Bf,
    const float* __restrict__ sq1, const float* __restrict__ sq2,
    u64* __restrict__ rowmin, u64* __restrict__ colmin)
{
    const int bid  = blockIdx.x;
    const int xcd  = bid & 7;
    const int t_   = bid >> 3;          // 0..767 per xcd
    const int kch  = t_ >> 6;           // 0..11  j-chunk index
    const int wdn  = t_ & 63;
    const int j0b  = (kch * 8 + (wdn & 7)) * 128;
    const int i0b  = (xcd * 8 + (wdn >> 3)) * 128;

    const int tid  = threadIdx.x;
    const int lane = tid & 63;
    const int wid  = tid >> 6;
    const int wr   = wid >> 1;
    const int wc   = wid & 1;
    const int lrow = lane & 15;
    const int lg   = lane >> 4;

    // Tile (rb, kc) at rb*6144 + kc*512 f16 (rb stride = 12 kc x 512).
    const _Float16* abase = Af + ((size_t)((i0b >> 4) + wr * 4) * 6144) + lane * 8;
    const _Float16* bbase = Bf + ((size_t)((j0b >> 4) + wc * 4) * 6144) + lane * 8;

    f32x4 acc[4][4];
    #pragma unroll
    for (int mi = 0; mi < 4; ++mi)
        #pragma unroll
        for (int ni = 0; ni < 4; ++ni)
            acc[mi][ni] = (f32x4){0.f, 0.f, 0.f, 0.f};

    #pragma unroll 1
    for (int kc = 0; kc < 12; ++kc) {
        const int ko = kc * 512;
        half8 bfr[4];
        #pragma unroll
        for (int ni = 0; ni < 4; ++ni)
            bfr[ni] = ld8h(bbase + ni * 6144 + ko);
        half8 a0, a1;
        a0 = ld8h(abase + ko);
        #pragma unroll
        for (int mi = 0; mi < 4; ++mi) {
            if (mi < 3)
                a1 = ld8h(abase + (mi + 1) * 6144 + ko);
            #pragma unroll
            for (int ni = 0; ni < 4; ++ni)
                acc[mi][ni] = __builtin_amdgcn_mfma_f32_16x16x32_f16(a0, bfr[ni], acc[mi][ni], 0, 0, 0);
            a0 = a1;
        }
    }

    // ---- epilogue: packed-min reductions (C/D: row=(lane>>4)*4+r+mi*16,
    // col=lane&15 + ni*16, within the wave's 64x64 tile) ----
    float q2v[4];
    #pragma unroll
    for (int ni = 0; ni < 4; ++ni)
        q2v[ni] = sq2[j0b + wc * 64 + ni * 16 + lrow];
    float4 q1v[4];
    #pragma unroll
    for (int mi = 0; mi < 4; ++mi)
        q1v[mi] = *(const float4*)(sq1 + i0b + wr * 64 + mi * 16 + 4 * lg);

    #pragma unroll
    for (int mi = 0; mi < 4; ++mi)
        #pragma unroll
        for (int r = 0; r < 4; ++r) {
            u64 best = ~0ull;
            #pragma unroll
            for (int ni = 0; ni < 4; ++ni) {
                float kr = fmaf(-2.f, acc[mi][ni][r], q2v[ni]);
                best = umin64(best, packkey(kr, (unsigned)(j0b + wc * 64 + ni * 16 + lrow)));
            }
            #pragma unroll
            for (int mask = 8; mask; mask >>= 1)
                best = umin64(best, __shfl_xor(best, mask));
            if (lrow == 0)
                atomicMin(&rowmin[i0b + wr * 64 + mi * 16 + 4 * lg + r], best);
        }

    #pragma unroll
    for (int ni = 0; ni < 4; ++ni) {
        u64 best = ~0ull;
        #pragma unroll
        for (int mi = 0; mi < 4; ++mi) {
            const float* q1p = (const float*)&q1v[mi];
            #pragma unroll
            for (int r = 0; r < 4; ++r) {
                float kc_ = fmaf(-2.f, acc[mi][ni][r], q1p[r]);
                best = umin64(best, packkey(kc_, (unsigned)(i0b + wr * 64 + mi * 16 + 4 * lg + r)));
            }
        }
        best = umin64(best, __shfl_xor(best, 16));
        best = umin64(best, __shfl_xor(best, 32));
        if (lane < 16)
            atomicMin(&colmin[j0b + wc * 64 + ni * 16 + lrow], best);
    }
}

// ============================ fallback path ============================
// In-kernel bf16 3-way split LDS version (round 5); needs no ws planes.
__global__ __launch_bounds__(256) void mfma_tile_kernel(
    const float* __restrict__ d1, const float* __restrict__ d2,
    const float* __restrict__ sq1, const float* __restrict__ sq2,
    u64* __restrict__ rowmin, u64* __restrict__ colmin)
{
    __shared__ __align__(16) short lds[6 * 4096];
    const int tid = threadIdx.x;
    const int i0b = blockIdx.y * 128;
    const int j0b = blockIdx.x * 128;
    const int srow  = tid >> 1;
    const int shalf = tid & 1;
    const int sfr   = fswz(srow);
    const int sg0   = ((2 * shalf) ^ sfr) * 8;
    const int sg1   = ((2 * shalf + 1) ^ sfr) * 8;
    const float* gA = d1 + (size_t)(i0b + srow) * DD + shalf * 16;
    const float* gB = d2 + (size_t)(j0b + srow) * DD + shalf * 16;
    short* wA = lds + srow * 32;
    short* wB = lds + 3 * 4096 + srow * 32;
    const int lane = tid & 63;
    const int wid  = tid >> 6;
    const int wr   = wid >> 1;
    const int wc   = wid & 1;
    const int lrow = lane & 15;
    const int lg   = lane >> 4;
    const int gx   = (lg ^ fswz(lrow)) * 8;
    const int aoff = (wr * 64 + lrow) * 32 + gx;
    const int boff = 3 * 4096 + (wc * 64 + lrow) * 32 + gx;

    f32x4 acc[4][4];
    #pragma unroll
    for (int mi = 0; mi < 4; ++mi)
        #pragma unroll
        for (int ni = 0; ni < 4; ++ni)
            acc[mi][ni] = (f32x4){0.f, 0.f, 0.f, 0.f};

    for (int kc = 0; kc < 4; ++kc) {
        {
            const float* sp = gA + kc * 32;
            short8 H0, M0, L0, H1, M1, L1;
            #pragma unroll
            for (int e = 0; e < 8; ++e) {
                float x = sp[e];
                ushort_t h = bf_rn(x); float r1 = x - bf_up(h);
                ushort_t m = bf_rn(r1); float r2 = r1 - bf_up(m);
                H0[e] = (short)h; M0[e] = (short)m; L0[e] = (short)bf_rn(r2);
            }
            #pragma unroll
            for (int e = 0; e < 8; ++e) {
                float x = sp[8 + e];
                ushort_t h = bf_rn(x); float r1 = x - bf_up(h);
                ushort_t m = bf_rn(r1); float r2 = r1 - bf_up(m);
                H1[e] = (short)h; M1[e] = (short)m; L1[e] = (short)bf_rn(r2);
            }
            *(short8*)(wA + sg0)        = H0;
            *(short8*)(wA + sg1)        = H1;
            *(short8*)(wA + 4096 + sg0) = M0;
            *(short8*)(wA + 4096 + sg1) = M1;
            *(short8*)(wA + 8192 + sg0) = L0;
            *(short8*)(wA + 8192 + sg1) = L1;
        }
        {
            const float* sp = gB + kc * 32;
            short8 H0, M0, L0, H1, M1, L1;
            #pragma unroll
            for (int e = 0; e < 8; ++e) {
                float x = sp[e];
                ushort_t h = bf_rn(x); float r1 = x - bf_up(h);
                ushort_t m = bf_rn(r1); float r2 = r1 - bf_up(m);
                H0[e] = (short)h; M0[e] = (short)m; L0[e] = (short)bf_rn(r2);
            }
            #pragma unroll
            for (int e = 0; e < 8; ++e) {
                float x = sp[8 + e];
                ushort_t h = bf_rn(x); float r1 = x - bf_up(h);
                ushort_t m = bf_rn(r1); float r2 = r1 - bf_up(m);
                H1[e] = (short)h; M1[e] = (short)m; L1[e] = (short)bf_rn(r2);
            }
            *(short8*)(wB + sg0)        = H0;
            *(short8*)(wB + sg1)        = H1;
            *(short8*)(wB + 4096 + sg0) = M0;
            *(short8*)(wB + 4096 + sg1) = M1;
            *(short8*)(wB + 8192 + sg0) = L0;
            *(short8*)(wB + 8192 + sg1) = L1;
        }
        __syncthreads();
        short8 af[3][4], bfr[3][4];
        #pragma unroll
        for (int c = 0; c < 3; ++c)
            #pragma unroll
            for (int t = 0; t < 4; ++t) {
                af[c][t]  = *(const short8*)(lds + c * 4096 + aoff + t * 512);
                bfr[c][t] = *(const short8*)(lds + c * 4096 + boff + t * 512);
            }
        #pragma unroll
        for (int mi = 0; mi < 4; ++mi)
            #pragma unroll
            for (int ni = 0; ni < 4; ++ni) {
                f32x4 a = acc[mi][ni];
                a = __builtin_amdgcn_mfma_f32_16x16x32_bf16(af[0][mi], bfr[0][ni], a, 0, 0, 0);
                a = __builtin_amdgcn_mfma_f32_16x16x32_bf16(af[0][mi], bfr[1][ni], a, 0, 0, 0);
                a = __builtin_amdgcn_mfma_f32_16x16x32_bf16(af[1][mi], bfr[0][ni], a, 0, 0, 0);
                a = __builtin_amdgcn_mfma_f32_16x16x32_bf16(af[0][mi], bfr[2][ni], a, 0, 0, 0);
                a = __builtin_amdgcn_mfma_f32_16x16x32_bf16(af[1][mi], bfr[1][ni], a, 0, 0, 0);
                a = __builtin_amdgcn_mfma_f32_16x16x32_bf16(af[2][mi], bfr[0][ni], a, 0, 0, 0);
                acc[mi][ni] = a;
            }
        __syncthreads();
    }

    float q2v[4];
    #pragma unroll
    for (int ni = 0; ni < 4; ++ni)
        q2v[ni] = sq2[j0b + wc * 64 + ni * 16 + lrow];
    float4 q1v[4];
    #pragma unroll
    for (int mi = 0; mi < 4; ++mi)
        q1v[mi] = *(const float4*)(sq1 + i0b + wr * 64 + mi * 16 + 4 * lg);

    #pragma unroll
    for (int mi = 0; mi < 4; ++mi)
        #pragma unroll
        for (int r = 0; r < 4; ++r) {
            u64 best = ~0ull;
            #pragma unroll
            for (int ni = 0; ni < 4; ++ni) {
                float kr = fmaf(-2.f, acc[mi][ni][r], q2v[ni]);
                best = umin64(best, packkey(kr, (unsigned)(j0b + wc * 64 + ni * 16 + lrow)));
            }
            #pragma unroll
            for (int mask = 8; mask; mask >>= 1)
                best = umin64(best, __shfl_xor(best, mask));
            if (lrow == 0)
                atomicMin(&rowmin[i0b + wr * 64 + mi * 16 + 4 * lg + r], best);
        }
    #pragma unroll
    for (int ni = 0; ni < 4; ++ni) {
        u64 best = ~0ull;
        #pragma unroll
        for (int mi = 0; mi < 4; ++mi) {
            const float* q1p = (const float*)&q1v[mi];
            #pragma unroll
            for (int r = 0; r < 4; ++r) {
                float kc_ = fmaf(-2.f, acc[mi][ni][r], q1p[r]);
                best = umin64(best, packkey(kc_, (unsigned)(i0b + wr * 64 + mi * 16 + 4 * lg + r)));
            }
        }
        best = umin64(best, __shfl_xor(best, 16));
        best = umin64(best, __shfl_xor(best, 32));
        if (lane < 16)
            atomicMin(&colmin[j0b + wc * 64 + ni * 16 + lrow], best);
    }
}

// Kernel 3: assemble outputs (bigf() instead of +inf: inf-inf = NaN fails diff).
__global__ __launch_bounds__(256) void final_kernel(
    const float* __restrict__ sq1,
    const u64* __restrict__ rowmin, const u64* __restrict__ colmin,
    float* __restrict__ out) {
    int i = blockIdx.x * 256 + threadIdx.x;
    if (i >= NB1) return;
    u64 rm = rowmin[i];
    unsigned ju = (unsigned)(rm & 0xFFFFFFFFu);
    float kr = unorderbits((unsigned)(rm >> 32));
    float dist = sqrtf(fmaxf(sq1[i] + kr, 0.f));
    dist = fminf(dist, bigf());
    bool valid = (ju < (unsigned)NB2);
    int j = valid ? (int)ju : 0;
    u64 cm = colmin[j];
    int i2 = (int)(cm & 0xFFFFFFFFu);
    bool mut = valid && (i2 == i);
    out[i] = mut ? dist : bigf();
    out[NB1 + 2 * i]     = mut ? (float)i : -1.f;
    out[NB1 + 2 * i + 1] = mut ? (float)j : -1.f;
    out[NB1 + 2 * NB1 + i] = mut ? 1.f : 0.f;
}

extern "C" void kernel_launch(void* const* d_in, const int* in_sizes, int n_in,
                              void* d_out, int out_size, void* d_ws, size_t ws_size,
                              hipStream_t stream) {
    const float* d1 = (const float*)d_in[0];
    const float* d2 = (const float*)d_in[1];
    float* out = (float*)d_out;

    char* ws = (char*)d_ws;
    float* sq1    = (float*)(ws);
    float* sq2    = (float*)(ws + 32768);
    u64*   rowmin = (u64*)(ws + 81920);
    u64*   colmin = (u64*)(ws + 147456);
    _Float16* Af = (_Float16*)(ws + 245760);            // 512*12*512*2  = 6,291,456 B
    _Float16* Bf = (_Float16*)(ws + 245760 + 6291456);  // 768*12*512*2  = 9,437,184 B
    const size_t need = 245760 + 6291456 + 9437184;     // ~15.2 MB

    hipLaunchKernelGGL(prep_kernel, dim3((NB2 + 255) / 256), dim3(256), 0, stream,
                       d1, d2, sq1, sq2, rowmin, colmin);
    if (ws_size >= need) {
        hipLaunchKernelGGL(split_ext16_kernel, dim3(3840), dim3(256), 0, stream,
                           d1, d2, Af, Bf);
        hipLaunchKernelGGL(mfma_tile7_kernel, dim3(6144), dim3(256), 0, stream,
                           Af, Bf, sq1, sq2, rowmin, colmin);
    } else {
        hipLaunchKernelGGL(mfma_tile_kernel, dim3(NB2 / 128, NB1 / 128), dim3(256), 0, stream,
                           d1, d2, sq1, sq2, rowmin, colmin);
    }
    hipLaunchKernelGGL(final_kernel, dim3((NB1 + 255) / 256), dim3(256), 0, stream,
                       sq1, rowmin, colmin, out);
}